// Round 1
// 150.728 us; speedup vs baseline: 1.1029x; 1.1029x over previous
//
#include <hip/hip_runtime.h>
#include <math.h>

// Problem constants
static constexpr int Bn   = 32;
static constexpr int Tn   = 512;
static constexpr int Cn   = 128;
static constexpr int NLAG = 57;   // lags 8..64 inclusive
static constexpr int CYC  = 64;   // CYC_MAX

// ---------------------------------------------------------------------------
// K1: circular autocorrelation partials. Logical work (b, lag-group of 8).
// XCD swizzle: hardware round-robins blockIdx%8 across XCDs; renumber so each
// XCD owns 4 consecutive b (working set 4x256KB = 1MB < 4MB L2, no thrash).
// ---------------------------------------------------------------------------
__global__ __launch_bounds__(256) void k_autocorr(const float* __restrict__ x,
    float* __restrict__ r_ws) {
  const int w   = (blockIdx.x & 7) * 32 + (blockIdx.x >> 3);  // bijective 0..255
  const int b   = w >> 3;
  const int grp = w & 7;
  const int L0  = 8 + grp * 8;
  const int tid = threadIdx.x;
  const float4* X4 = (const float4*)(x + (size_t)b * Tn * Cn);  // [512][32]

  float acc[8];
#pragma unroll
  for (int i = 0; i < 8; ++i) acc[i] = 0.f;

  for (int it = 0; it < 8; ++it) {
    const int id = it * 256 + tid;
    const int c4 = id & 31;
    const int t0 = (id >> 5) * 8;
    float4 A[8];
#pragma unroll
    for (int j = 0; j < 8; ++j) A[j] = X4[(t0 + j) * 32 + c4];
    float4 R[16];
#pragma unroll
    for (int j = 0; j < 16; ++j) R[j] = X4[((t0 + L0 + j) & 511) * 32 + c4];
#pragma unroll
    for (int g = 0; g < 8; ++g) {
#pragma unroll
      for (int j = 0; j < 8; ++j) {
        const float4 a = A[j];
        const float4 r = R[g + j];
        acc[g] += a.x * r.x + a.y * r.y + a.z * r.z + a.w * r.w;
      }
    }
  }

  __shared__ float lds_r[4][8];
  const int lane = tid & 63, wave = tid >> 6;
#pragma unroll
  for (int g = 0; g < 8; ++g) {
    float v = acc[g];
#pragma unroll
    for (int m = 32; m > 0; m >>= 1) v += __shfl_xor(v, m, 64);
    if (lane == 0) lds_r[wave][g] = v;
  }
  __syncthreads();
  if (tid < 8) {
    const int li = grp * 8 + tid;
    if (li < NLAG) {
      r_ws[b * NLAG + li] =
          (lds_r[0][tid] + lds_r[1][tid] + lds_r[2][tid] + lds_r[3][tid]) * (1.0f / Cn);
    }
  }
}

// ---------------------------------------------------------------------------
// K2: fused fold + depthwise conv + pointwise conv + GN + gelu + gate.
// One block per n (=b*3+k), 512 threads (8 waves). Top-3 recomputed in-block
// (wave-parallel argmax over r_ws), fold done straight into LDS (no u tensor,
// no 8x staging redundancy).
// LDS: su[64][129] (u, pad->2-way-free column reads), sh[128][65] (h1).
// ---------------------------------------------------------------------------
__global__ __launch_bounds__(512) void k_fold_conv(
    const float* __restrict__ x, const float* __restrict__ r_ws,
    const float* __restrict__ Wdw, const float* __restrict__ Wpw,
    const float* __restrict__ gnw, const float* __restrict__ gnb,
    const float* __restrict__ Wgate, float* __restrict__ hh) {
  // XCD swizzle: co-locate the 3 blocks of each b (and 4 b's) per XCD.
  const int n  = (blockIdx.x & 7) * 12 + (blockIdx.x >> 3);   // bijective 0..95
  const int b  = n / 3, kk = n % 3;
  const int tid  = threadIdx.x;
  const int lane = tid & 63;
  const int wq   = __builtin_amdgcn_readfirstlane(tid >> 6);  // wave id 0..7

  __shared__ float su[CYC * 129];
  __shared__ float sh[Cn * 65];
  __shared__ float ubar_s[Cn];
  __shared__ float gates_s[Cn];
  __shared__ int   p_sh;

  // ---- top-(kk+1) argmax over 57 lags, wave 0 only, smallest-index ties ----
  if (tid < 64) {
    const float* rb = r_ws + b * NLAG;
    float v  = (tid < NLAG) ? rb[tid] : -INFINITY;
    int  idx = tid;
    int  lag = 8;
#pragma unroll
    for (int k = 0; k < 3; ++k) {
      if (k > kk) break;
      float bv = v; int bi = idx;
#pragma unroll
      for (int m = 32; m > 0; m >>= 1) {
        const float ov = __shfl_xor(bv, m, 64);
        const int   oi = __shfl_xor(bi, m, 64);
        if (ov > bv || (ov == bv && oi < bi)) { bv = ov; bi = oi; }
      }
      lag = bi + 8;
      if (idx == bi) v = -INFINITY;
    }
    if (tid == 0) p_sh = lag;
  }
  __syncthreads();
  const int p    = p_sh;
  const int ncyc = (Tn + p - 1) / p;

  // ---- fold: thread owns row l = tid>>3, 16 channels c0 = (tid&7)*16 ----
  {
    const int l  = tid >> 3;
    const int c0 = (tid & 7) * 16;
    float a[16];
#pragma unroll
    for (int i = 0; i < 16; ++i) a[i] = 0.f;
    if (l < ncyc) {
      const float4* xb4 = (const float4*)(x + (size_t)b * Tn * Cn) + (c0 >> 2);
      const int base = l * p;
      for (int j = 0; j < p; ++j) {
        const int time = base + j;
        const int src  = time < Tn ? time : (2 * (Tn - 1) - time);
        const float4 v0 = xb4[src * 32 + 0];
        const float4 v1 = xb4[src * 32 + 1];
        const float4 v2 = xb4[src * 32 + 2];
        const float4 v3 = xb4[src * 32 + 3];
        a[0]  += v0.x; a[1]  += v0.y; a[2]  += v0.z; a[3]  += v0.w;
        a[4]  += v1.x; a[5]  += v1.y; a[6]  += v1.z; a[7]  += v1.w;
        a[8]  += v2.x; a[9]  += v2.y; a[10] += v2.z; a[11] += v2.w;
        a[12] += v3.x; a[13] += v3.y; a[14] += v3.z; a[15] += v3.w;
      }
    }
    float* dst = su + l * 129 + c0;
#pragma unroll
    for (int i = 0; i < 16; ++i) dst[i] = a[i] * (1.0f / 64.0f);
  }
  __syncthreads();

  // ---- ubar[c] = mean over l (waves 0-1) ----
  if (tid < Cn) {
    float s = 0.f;
    for (int l = 0; l < CYC; ++l) s += su[l * 129 + tid];
    ubar_s[tid] = s * (1.0f / CYC);
  }

  // ---- depthwise conv: wave wq covers c = wq*16..+16, lane = l ----
  {
    const int c0 = wq * 16;
#pragma unroll
    for (int i = 0; i < 16; ++i) {
      const int c = c0 + i;
      float s = 0.f;
#pragma unroll
      for (int k = 0; k < 9; ++k) {
        const int ll = lane + k - 4;
        if (ll >= 0 && ll < CYC) s += su[ll * 129 + c] * Wdw[c * 9 + k];
      }
      sh[c * 65 + lane] = s;
    }
  }
  __syncthreads();   // sh complete + ubar_s visible

  // ---- gates: wave wq computes its own 16 outputs, 4-lane partials ----
  {
    const int ol   = lane & 15;
    const int part = lane >> 4;
    const int o    = wq * 16 + ol;
    float z = 0.f;
    const float* wg = Wgate + (size_t)o * Cn + part * 32;
    const float* ub = ubar_s + part * 32;
    for (int c = 0; c < 32; ++c) z += wg[c] * ub[c];
    z += __shfl_xor(z, 16, 64);
    z += __shfl_xor(z, 32, 64);
    if (part == 0) gates_s[o] = 1.0f / (1.0f + expf(-z));
  }

  // ---- pointwise conv: wave wq -> outputs o0 = wq*16 .. +16 ----
  float acc[16];
#pragma unroll
  for (int i = 0; i < 16; ++i) acc[i] = 0.f;
  const int o0 = wq * 16;
  {
    const float* wb = Wpw + (size_t)o0 * Cn;
    for (int c = 0; c < Cn; ++c) {
      const float hv = sh[c * 65 + lane];
#pragma unroll
      for (int i = 0; i < 16; ++i) acc[i] = fmaf(wb[i * Cn + c], hv, acc[i]);
    }
  }
  __syncthreads();   // gates_s fully published

  // ---- GN (4 channels x 64 l per group; this wave's 16 o = 4 groups) ----
  float4 res[4];
#pragma unroll
  for (int g = 0; g < 4; ++g) {
    float s1 = acc[4*g] + acc[4*g+1] + acc[4*g+2] + acc[4*g+3];
    float s2 = acc[4*g]*acc[4*g] + acc[4*g+1]*acc[4*g+1]
             + acc[4*g+2]*acc[4*g+2] + acc[4*g+3]*acc[4*g+3];
#pragma unroll
    for (int m = 32; m > 0; m >>= 1) {
      s1 += __shfl_xor(s1, m, 64);
      s2 += __shfl_xor(s2, m, 64);
    }
    const float mean = s1 * (1.0f / 256.0f);
    const float var  = s2 * (1.0f / 256.0f) - mean * mean;
    const float rstd = rsqrtf(var + 1e-5f);
    float* rp = (float*)&res[g];
#pragma unroll
    for (int i = 0; i < 4; ++i) {
      const int o = o0 + 4*g + i;
      float h = (acc[4*g + i] - mean) * rstd;
      h = h * gnw[o] + gnb[o];
      h = 0.5f * h * (1.0f + erff(h * 0.70710678118654752440f));
      rp[i] = h * gates_s[o];
    }
  }
  float4* hp = (float4*)(hh + (size_t)n * CYC * Cn + (size_t)lane * Cn + o0);
#pragma unroll
  for (int g = 0; g < 4; ++g) hp[g] = res[g];
}

// ---------------------------------------------------------------------------
// K3: fused dot + out. Block = (b, c-group of 16), grid (32, 8): blockIdx.x=b
// so a batch's 8 blocks share an XCD. Pass1: P -> LDS, accumulate num/den
// per c; reduce; Pass2: out = x - sc*P (no hh re-gather).
// ---------------------------------------------------------------------------
__global__ __launch_bounds__(128) void k_dot_out(
    const float* __restrict__ x, const float* __restrict__ hh,
    const float* __restrict__ r_ws, const float* __restrict__ gamma,
    float* __restrict__ out) {
  const int b  = blockIdx.x;   // 0..31
  const int cg = blockIdx.y;   // 0..7
  const int tid = threadIdx.x;
  const int c_l = tid & 15;
  const int tg  = tid >> 4;          // 8 groups x 64 t
  const int c   = cg * 16 + c_l;

  __shared__ float P_s[Tn * 16];           // 32 KB
  __shared__ unsigned short cyc_s[Tn][3];  // 3 KB
  __shared__ float params[4];              // w0,w1,w2,g
  __shared__ int   pp[3];
  __shared__ float red[2][2][16];
  __shared__ float sc_s[16];

  // ---- wave-parallel top-3 + softmax + Gamma ----
  if (tid < 64) {
    const float* rb = r_ws + b * NLAG;
    float v  = (tid < NLAG) ? rb[tid] : -INFINITY;
    int  idx = tid;
    float vals[3]; int lags[3];
#pragma unroll
    for (int k = 0; k < 3; ++k) {
      float bv = v; int bi = idx;
#pragma unroll
      for (int m = 32; m > 0; m >>= 1) {
        const float ov = __shfl_xor(bv, m, 64);
        const int   oi = __shfl_xor(bi, m, 64);
        if (ov > bv || (ov == bv && oi < bi)) { bv = ov; bi = oi; }
      }
      vals[k] = bv; lags[k] = bi + 8;
      if (idx == bi) v = -INFINITY;
    }
    if (tid == 0) {
      const float m  = vals[0];
      const float e0 = expf(vals[0] - m), e1 = expf(vals[1] - m), e2 = expf(vals[2] - m);
      const float s  = e0 + e1 + e2;
      const float w0 = e0 / s, w1 = e1 / s, w2 = e2 / s;
      pp[0] = lags[0]; pp[1] = lags[1]; pp[2] = lags[2];
      params[0] = w0; params[1] = w1; params[2] = w2;
      const float H  = -(w0 * logf(w0 + 1e-8f) + w1 * logf(w1 + 1e-8f) + w2 * logf(w2 + 1e-8f));
      const float lg = logf(3.0f + 1e-8f) + 1e-8f;
      params[3] = fminf(fmaxf(1.0f - H / lg, 0.0f), 1.0f);
    }
  }
  __syncthreads();
  const int p0 = pp[0], p1 = pp[1], p2 = pp[2];
  const float w0 = params[0], w1 = params[1], w2 = params[2];
  const float g  = params[3];
  const float sw = w0 + w1 + w2;

  for (int t = tid; t < Tn; t += 128) {
    cyc_s[t][0] = (unsigned short)(t / p0);
    cyc_s[t][1] = (unsigned short)(t / p1);
    cyc_s[t][2] = (unsigned short)(t / p2);
  }
  __syncthreads();

  const float gam = gamma[c];
  const float* xb = x + (size_t)b * Tn * Cn;
  const float* h0 = hh + (size_t)(b * 3 + 0) * CYC * Cn + c;
  const float* h1 = hh + (size_t)(b * 3 + 1) * CYC * Cn + c;
  const float* h2 = hh + (size_t)(b * 3 + 2) * CYC * Cn + c;

  float na = 0.f, da = 0.f;
  for (int tt = 0; tt < 64; ++tt) {
    const int t = (tg << 6) + tt;
    const float xv = xb[t * Cn + c];
    const float dv = gam * (w0 * h0[cyc_s[t][0] * Cn] +
                            w1 * h1[cyc_s[t][1] * Cn] +
                            w2 * h2[cyc_s[t][2] * Cn]);
    const float P = sw * xv + dv;
    P_s[t * 16 + c_l] = P;
    na += (xv - P) * P;
    da += P * P;
  }
  // reduce over 4 tg within wave, then 2 waves via LDS
  na += __shfl_xor(na, 16, 64); da += __shfl_xor(da, 16, 64);
  na += __shfl_xor(na, 32, 64); da += __shfl_xor(da, 32, 64);
  const int wv_ = tid >> 6;
  if ((tid & 63) < 16) { red[0][wv_][c_l] = na; red[1][wv_][c_l] = da; }
  __syncthreads();
  if (tid < 16) {
    const float num = red[0][0][tid] + red[0][1][tid];
    const float den = red[1][0][tid] + red[1][1][tid] + 1e-6f;
    sc_s[tid] = g * (num / den);
  }
  __syncthreads();
  const float sc = sc_s[c_l];

  float* ob = out + (size_t)b * Tn * Cn;
  for (int tt = 0; tt < 64; ++tt) {
    const int t = (tg << 6) + tt;
    const float xv = xb[t * Cn + c];
    ob[t * Cn + c] = xv - sc * P_s[t * 16 + c_l];
  }
}

// ---------------------------------------------------------------------------
extern "C" void kernel_launch(void* const* d_in, const int* in_sizes, int n_in,
                              void* d_out, int out_size, void* d_ws, size_t ws_size,
                              hipStream_t stream) {
  const float* x     = (const float*)d_in[0];
  const float* Wdw   = (const float*)d_in[1];
  const float* Wpw   = (const float*)d_in[2];
  const float* gnw   = (const float*)d_in[3];
  const float* gnb   = (const float*)d_in[4];
  const float* Wgate = (const float*)d_in[5];
  const float* gamma = (const float*)d_in[6];
  float* out = (float*)d_out;

  char* ws = (char*)d_ws;
  float* r_ws = (float*)ws;             // 32*57 floats
  float* hh   = (float*)(ws + 8192);    // 96*64*128 floats (3 MB)

  k_autocorr<<<Bn * 8, 256, 0, stream>>>(x, r_ws);
  k_fold_conv<<<Bn * 3, 512, 0, stream>>>(x, r_ws, Wdw, Wpw, gnw, gnb, Wgate, hh);
  k_dot_out<<<dim3(Bn, 8), 128, 0, stream>>>(x, hh, r_ws, gamma, out);
}

// Round 2
// 138.914 us; speedup vs baseline: 1.1967x; 1.0850x over previous
//
#include <hip/hip_runtime.h>
#include <math.h>

// Problem constants
static constexpr int Bn   = 32;
static constexpr int Tn   = 512;
static constexpr int Cn   = 128;
static constexpr int NLAG = 57;   // lags 8..64 inclusive
static constexpr int CYC  = 64;   // CYC_MAX

// ---------------------------------------------------------------------------
// Wave-parallel top-(kk+1) argmax over r_ws[b] (57 lags). Call with tid<64.
// Matches lax.top_k tie-break (smallest index wins on equal values).
// ---------------------------------------------------------------------------
__device__ __forceinline__ int topk_p(const float* __restrict__ rb,
                                      int tid, int kk) {
  float v  = (tid < NLAG) ? rb[tid] : -INFINITY;
  int  idx = tid;
  int  lag = 8;
#pragma unroll
  for (int k = 0; k < 3; ++k) {
    if (k > kk) break;
    float bv = v; int bi = idx;
#pragma unroll
    for (int m = 32; m > 0; m >>= 1) {
      const float ov = __shfl_xor(bv, m, 64);
      const int   oi = __shfl_xor(bi, m, 64);
      if (ov > bv || (ov == bv && oi < bi)) { bv = ov; bi = oi; }
    }
    lag = bi + 8;
    if (idx == bi) v = -INFINITY;
  }
  return lag;
}

// ---------------------------------------------------------------------------
// K1: circular autocorrelation. Logical work (b, lag-group of 8).
// XCD swizzle: each XCD owns 4 consecutive b (1MB working set < 4MB L2).
// ---------------------------------------------------------------------------
__global__ __launch_bounds__(256) void k_autocorr(const float* __restrict__ x,
    float* __restrict__ r_ws) {
  const int w   = (blockIdx.x & 7) * 32 + (blockIdx.x >> 3);  // bijective 0..255
  const int b   = w >> 3;
  const int grp = w & 7;
  const int L0  = 8 + grp * 8;
  const int tid = threadIdx.x;
  const float4* X4 = (const float4*)(x + (size_t)b * Tn * Cn);  // [512][32]

  float acc[8];
#pragma unroll
  for (int i = 0; i < 8; ++i) acc[i] = 0.f;

  for (int it = 0; it < 8; ++it) {
    const int id = it * 256 + tid;
    const int c4 = id & 31;
    const int t0 = (id >> 5) * 8;
    float4 A[8];
#pragma unroll
    for (int j = 0; j < 8; ++j) A[j] = X4[(t0 + j) * 32 + c4];
    float4 R[16];
#pragma unroll
    for (int j = 0; j < 16; ++j) R[j] = X4[((t0 + L0 + j) & 511) * 32 + c4];
#pragma unroll
    for (int g = 0; g < 8; ++g) {
#pragma unroll
      for (int j = 0; j < 8; ++j) {
        const float4 a = A[j];
        const float4 r = R[g + j];
        acc[g] += a.x * r.x + a.y * r.y + a.z * r.z + a.w * r.w;
      }
    }
  }

  __shared__ float lds_r[4][8];
  const int lane = tid & 63, wave = tid >> 6;
#pragma unroll
  for (int g = 0; g < 8; ++g) {
    float v = acc[g];
#pragma unroll
    for (int m = 32; m > 0; m >>= 1) v += __shfl_xor(v, m, 64);
    if (lane == 0) lds_r[wave][g] = v;
  }
  __syncthreads();
  if (tid < 8) {
    const int li = grp * 8 + tid;
    if (li < NLAG) {
      r_ws[b * NLAG + li] =
          (lds_r[0][tid] + lds_r[1][tid] + lds_r[2][tid] + lds_r[3][tid]) * (1.0f / Cn);
    }
  }
}

// ---------------------------------------------------------------------------
// K2: fold. One block per (n, l): 6144 blocks of 128 threads (thread = c).
// Massive TLP hides the serial j<p global-load chain. In-block argmax for p.
// XCD swizzle: 12 consecutive n per XCD (x slice 1MB in L2).
// ---------------------------------------------------------------------------
__global__ __launch_bounds__(128) void k_fold_u(const float* __restrict__ x,
    const float* __restrict__ r_ws, float* __restrict__ u) {
  const int bid = blockIdx.x;                       // 0..6143
  const int w = (bid & 7) * 768 + (bid >> 3);       // bijective
  const int n = w >> 6, l = w & 63;
  const int b = n / 3, kk = n % 3;
  const int tid = threadIdx.x;

  __shared__ int p_sh;
  if (tid < 64) {
    const int lag = topk_p(r_ws + b * NLAG, tid, kk);
    if (tid == 0) p_sh = lag;
  }
  __syncthreads();
  const int p    = p_sh;
  const int ncyc = (Tn + p - 1) / p;

  float acc = 0.f;
  if (l < ncyc) {
    const float* xb = x + (size_t)b * Tn * Cn;
    const int base = l * p;
    for (int j = 0; j < p; ++j) {
      const int time = base + j;
      const int src  = time < Tn ? time : (2 * (Tn - 1) - time);
      acc += xb[src * Cn + tid];
    }
  }
  u[((size_t)n * CYC + l) * Cn + tid] = acc * (1.0f / 64.0f);
}

// ---------------------------------------------------------------------------
// K3: conv chain (dw + pw + GN + gelu + gate). p-independent (GN/gate stats
// are over the full 64x64 grid per reference). Grid: 768 blocks (n=96, og=8),
// 256 threads = 4 waves; wave wq: dw for c=wq*32..+32, pw for o=og*16+wq*4..+4.
// LDS: one 8320-float buffer: u-view [64][129], then h1-view [128][65].
// XCD swizzle: 12 consecutive n (x8 og) per XCD -> u slice 384KB in L2.
// ---------------------------------------------------------------------------
__global__ __launch_bounds__(256) void k_conv(
    const float* __restrict__ u, const float* __restrict__ Wdw,
    const float* __restrict__ Wpw, const float* __restrict__ gnw,
    const float* __restrict__ gnb, const float* __restrict__ Wgate,
    float* __restrict__ hh) {
  const int bid = blockIdx.x;                      // 0..767
  const int w = (bid & 7) * 96 + (bid >> 3);       // bijective
  const int n = w >> 3, og = w & 7;
  const int tid  = threadIdx.x;
  const int l    = tid & 63;
  const int wq   = __builtin_amdgcn_readfirstlane(tid >> 6);

  __shared__ float smem[8320];     // u-view [l][129]; h1-view [c][65]
  __shared__ float ubar_s[Cn];

  // stage u[n] (32KB): float4 global loads, scalar LDS writes into pad-129
  {
    const float4* u4 = (const float4*)(u + (size_t)n * CYC * Cn);
#pragma unroll
    for (int i = 0; i < 8; ++i) {
      const int idx4 = i * 256 + tid;      // 0..2047
      const float4 v = u4[idx4];
      const int ll = idx4 >> 5;
      const int cc = (idx4 & 31) << 2;
      float* d = smem + ll * 129 + cc;
      d[0] = v.x; d[1] = v.y; d[2] = v.z; d[3] = v.w;
    }
  }
  __syncthreads();

  // ubar[c] = mean over l (threads 0..127); stride-129 columns conflict-free
  if (tid < Cn) {
    float s = 0.f;
    for (int ll = 0; ll < CYC; ++ll) s += smem[ll * 129 + tid];
    ubar_s[tid] = s * (1.0f / CYC);
  }

  // depthwise conv -> registers: thread (l, wq) covers c = wq*32 .. +32
  float hreg[32];
  {
    const int c0 = wq * 32;
#pragma unroll
    for (int i = 0; i < 32; ++i) {
      const int c = c0 + i;
      float s = 0.f;
#pragma unroll
      for (int k = 0; k < 9; ++k) {
        const int ll = l + k - 4;
        if (ll >= 0 && ll < CYC) s += smem[ll * 129 + c] * Wdw[c * 9 + k];
      }
      hreg[i] = s;
    }
  }
  __syncthreads();   // all su reads done; ubar_s visible

  // gates: each wave computes its own 4 outputs; 16 lane-groups x 8 channels
  float gi[4];
  {
    const int ol   = l & 3;
    const int part = l >> 2;               // 0..15
    const int o    = og * 16 + wq * 4 + ol;
    float z = 0.f;
    const float* wg = Wgate + (size_t)o * Cn + part * 8;
    const float* ub = ubar_s + part * 8;
#pragma unroll
    for (int cc = 0; cc < 8; ++cc) z += wg[cc] * ub[cc];
    z += __shfl_xor(z, 4, 64);
    z += __shfl_xor(z, 8, 64);
    z += __shfl_xor(z, 16, 64);
    z += __shfl_xor(z, 32, 64);
    const float sig = 1.0f / (1.0f + expf(-z));
#pragma unroll
    for (int i = 0; i < 4; ++i) gi[i] = __shfl(sig, i, 64);
  }

  // overwrite LDS with h1-view [c][65]
  {
    const int c0 = wq * 32;
#pragma unroll
    for (int i = 0; i < 32; ++i) smem[(c0 + i) * 65 + l] = hreg[i];
  }
  __syncthreads();

  // pointwise: 4 outputs per wave
  const int o4 = og * 16 + wq * 4;
  float acc[4];
#pragma unroll
  for (int i = 0; i < 4; ++i) acc[i] = 0.f;
  const float* wb = Wpw + (size_t)o4 * Cn;
  for (int c = 0; c < Cn; ++c) {
    const float hv = smem[c * 65 + l];
#pragma unroll
    for (int i = 0; i < 4; ++i) acc[i] = fmaf(wb[i * Cn + c], hv, acc[i]);
  }

  // GroupNorm: this wave's 4 o == exactly one GN group (4 ch x 64 l)
  float s1 = acc[0] + acc[1] + acc[2] + acc[3];
  float s2 = acc[0]*acc[0] + acc[1]*acc[1] + acc[2]*acc[2] + acc[3]*acc[3];
#pragma unroll
  for (int m = 32; m > 0; m >>= 1) {
    s1 += __shfl_xor(s1, m, 64);
    s2 += __shfl_xor(s2, m, 64);
  }
  const float mean = s1 * (1.0f / 256.0f);
  const float var  = s2 * (1.0f / 256.0f) - mean * mean;
  const float rstd = rsqrtf(var + 1e-5f);

  float4 res;
  float* rp = (float*)&res;
#pragma unroll
  for (int i = 0; i < 4; ++i) {
    const int o = o4 + i;
    float h = (acc[i] - mean) * rstd;
    h = h * gnw[o] + gnb[o];
    h = 0.5f * h * (1.0f + erff(h * 0.70710678118654752440f));
    rp[i] = h * gi[i];
  }
  *(float4*)(hh + (size_t)n * CYC * Cn + (size_t)l * Cn + o4) = res;
}

// ---------------------------------------------------------------------------
// K4: fused dot + out. 256 blocks (b=32, cg=8), 256 threads: c_l = tid&15,
// tg = tid>>4 (16 groups). t = tt*16+tg interleave -> P_s access is exactly
// 2-way LDS aliasing (free). Pass1 P->LDS + num/den; reduce; Pass2 writes.
// XCD swizzle: 4 consecutive b per XCD.
// ---------------------------------------------------------------------------
__global__ __launch_bounds__(256) void k_dot_out(
    const float* __restrict__ x, const float* __restrict__ hh,
    const float* __restrict__ r_ws, const float* __restrict__ gamma,
    float* __restrict__ out) {
  const int bid = blockIdx.x;                     // 0..255
  const int w = (bid & 7) * 32 + (bid >> 3);      // bijective
  const int b = w >> 3, cg = w & 7;
  const int tid = threadIdx.x;
  const int c_l = tid & 15;
  const int tg  = tid >> 4;          // 0..15
  const int c   = cg * 16 + c_l;

  __shared__ float P_s[Tn * 16];           // 32 KB
  __shared__ unsigned short cyc_s[Tn][3];
  __shared__ float params[4];              // w0,w1,w2,g
  __shared__ int   pp[3];
  __shared__ float red[2][4][16];
  __shared__ float sc_s[16];

  // ---- wave-parallel top-3 + softmax + Gamma ----
  if (tid < 64) {
    const float* rb = r_ws + b * NLAG;
    float v  = (tid < NLAG) ? rb[tid] : -INFINITY;
    int  idx = tid;
    float vals[3]; int lags[3];
#pragma unroll
    for (int k = 0; k < 3; ++k) {
      float bv = v; int bi = idx;
#pragma unroll
      for (int m = 32; m > 0; m >>= 1) {
        const float ov = __shfl_xor(bv, m, 64);
        const int   oi = __shfl_xor(bi, m, 64);
        if (ov > bv || (ov == bv && oi < bi)) { bv = ov; bi = oi; }
      }
      vals[k] = bv; lags[k] = bi + 8;
      if (idx == bi) v = -INFINITY;
    }
    if (tid == 0) {
      const float m  = vals[0];
      const float e0 = expf(vals[0] - m), e1 = expf(vals[1] - m), e2 = expf(vals[2] - m);
      const float s  = e0 + e1 + e2;
      const float w0 = e0 / s, w1 = e1 / s, w2 = e2 / s;
      pp[0] = lags[0]; pp[1] = lags[1]; pp[2] = lags[2];
      params[0] = w0; params[1] = w1; params[2] = w2;
      const float H  = -(w0 * logf(w0 + 1e-8f) + w1 * logf(w1 + 1e-8f) + w2 * logf(w2 + 1e-8f));
      const float lg = logf(3.0f + 1e-8f) + 1e-8f;
      params[3] = fminf(fmaxf(1.0f - H / lg, 0.0f), 1.0f);
    }
  }
  __syncthreads();
  const int p0 = pp[0], p1 = pp[1], p2 = pp[2];
  const float w0 = params[0], w1 = params[1], w2 = params[2];
  const float g  = params[3];
  const float sw = w0 + w1 + w2;

  for (int t = tid; t < Tn; t += 256) {
    cyc_s[t][0] = (unsigned short)(t / p0);
    cyc_s[t][1] = (unsigned short)(t / p1);
    cyc_s[t][2] = (unsigned short)(t / p2);
  }
  __syncthreads();

  const float gam = gamma[c];
  const float* xb = x + (size_t)b * Tn * Cn;
  const float* h0 = hh + (size_t)(b * 3 + 0) * CYC * Cn + c;
  const float* h1 = hh + (size_t)(b * 3 + 1) * CYC * Cn + c;
  const float* h2 = hh + (size_t)(b * 3 + 2) * CYC * Cn + c;

  float na = 0.f, da = 0.f;
#pragma unroll 4
  for (int tt = 0; tt < 32; ++tt) {
    const int t = tt * 16 + tg;
    const float xv = xb[t * Cn + c];
    const float dv = gam * (w0 * h0[cyc_s[t][0] * Cn] +
                            w1 * h1[cyc_s[t][1] * Cn] +
                            w2 * h2[cyc_s[t][2] * Cn]);
    const float P = sw * xv + dv;
    P_s[t * 16 + c_l] = P;
    na += (xv - P) * P;
    da += P * P;
  }
  // reduce over 4 tg within wave, then 4 waves via LDS
  na += __shfl_xor(na, 16, 64); da += __shfl_xor(da, 16, 64);
  na += __shfl_xor(na, 32, 64); da += __shfl_xor(da, 32, 64);
  const int wv_ = tid >> 6;
  if ((tid & 63) < 16) { red[0][wv_][c_l] = na; red[1][wv_][c_l] = da; }
  __syncthreads();
  if (tid < 16) {
    const float num = red[0][0][tid] + red[0][1][tid] + red[0][2][tid] + red[0][3][tid];
    const float den = red[1][0][tid] + red[1][1][tid] + red[1][2][tid] + red[1][3][tid] + 1e-6f;
    sc_s[tid] = g * (num / den);
  }
  __syncthreads();
  const float sc = sc_s[c_l];

  float* ob = out + (size_t)b * Tn * Cn;
#pragma unroll 4
  for (int tt = 0; tt < 32; ++tt) {
    const int t = tt * 16 + tg;
    const float xv = xb[t * Cn + c];
    ob[t * Cn + c] = xv - sc * P_s[t * 16 + c_l];
  }
}

// ---------------------------------------------------------------------------
extern "C" void kernel_launch(void* const* d_in, const int* in_sizes, int n_in,
                              void* d_out, int out_size, void* d_ws, size_t ws_size,
                              hipStream_t stream) {
  const float* x     = (const float*)d_in[0];
  const float* Wdw   = (const float*)d_in[1];
  const float* Wpw   = (const float*)d_in[2];
  const float* gnw   = (const float*)d_in[3];
  const float* gnb   = (const float*)d_in[4];
  const float* Wgate = (const float*)d_in[5];
  const float* gamma = (const float*)d_in[6];
  float* out = (float*)d_out;

  char* ws = (char*)d_ws;
  float* r_ws = (float*)ws;                       // 32*57 floats
  float* u    = (float*)(ws + 8192);              // 96*64*128 floats (3 MB)
  float* hh   = (float*)(ws + 8192 + 3145728);    // 3 MB

  k_autocorr<<<Bn * 8, 256, 0, stream>>>(x, r_ws);
  k_fold_u<<<6144, 128, 0, stream>>>(x, r_ws, u);
  k_conv<<<768, 256, 0, stream>>>(u, Wdw, Wpw, gnw, gnb, Wgate, hh);
  k_dot_out<<<256, 256, 0, stream>>>(x, hh, r_ws, gamma, out);
}